// Round 3
// baseline (714.924 us; speedup 1.0000x reference)
//
#include <hip/hip_runtime.h>
#include <hip/hip_bf16.h>
#include <math.h>

#define N_PTS  100000
#define M_CL   2048
#define E_EDG  65536
#define IN_DIM 512
#define HID    256
// TAU = 0.5 -> 1/TAU = 2.0 ; LAMDA = 1.0 (folded)

typedef unsigned short u16;
typedef __attribute__((ext_vector_type(8))) short bf16x8;
typedef __attribute__((ext_vector_type(4))) float f32x4;

__device__ __forceinline__ u16 f2bf(float f){
  __hip_bfloat16 h = __float2bfloat16(f);
  return *reinterpret_cast<u16*>(&h);
}
__device__ __forceinline__ unsigned pk2(float a, float b){
  return (unsigned)f2bf(a) | ((unsigned)f2bf(b) << 16);
}
__device__ __forceinline__ bf16x8 cvt8(f32x4 lo, f32x4 hi){
  bf16x8 r;
  r[0]=(short)f2bf(lo.x); r[1]=(short)f2bf(lo.y); r[2]=(short)f2bf(lo.z); r[3]=(short)f2bf(lo.w);
  r[4]=(short)f2bf(hi.x); r[5]=(short)f2bf(hi.y); r[6]=(short)f2bf(hi.z); r[7]=(short)f2bf(hi.w);
  return r;
}

// ---------------- workspace layout (bytes) ----------------
static const size_t OFF_POSACC = 0;              // M floats
static const size_t OFF_NEGSUM = 8192;           // M floats
static const size_t OFF_HISTP  = 16384;          // M ints
static const size_t OFF_CURP   = 24576;          // M ints
static const size_t OFF_HISTE  = 32768;          // M ints
static const size_t OFF_CURE   = 40960;          // M ints
static const size_t OFF_LOSS   = 49152;          // 1 double
static const size_t ZERO_BYTES = 49408;
static const size_t OFF_STARTP = 49664;          // M+1 ints
static const size_t OFF_STARTE = 58112;          // M+1 ints
static const size_t OFF_SORTPT = 66560;          // N ints
static const size_t OFF_SCOL   = 466688;         // E ints
static const size_t OFF_SVAL   = 728832;         // E floats
static const size_t OFF_CNT    = 990976;         // M floats
static const size_t OFF_XC     = 999168;         // M*512 floats
static const size_t OFF_Q      = 9387776;        // M*256 floats
static const size_t OFF_HN     = 11484928;       // M*256 floats
static const size_t OFF_NEG    = 13582080;       // M*M floats = 16 MB
// bf16-transposed weights alias the NEG region: all consumers (k_mchain,
// k_target_mfma) complete before k_neg writes negbuf (stream-ordered).
static const size_t OFF_WT0T   = OFF_NEG;               // 256*512*2 = 256 KB
static const size_t OFF_WT1T   = OFF_NEG +  262144;     // 128 KB
static const size_t OFF_WE0T   = OFF_NEG +  393216;     // 256 KB
static const size_t OFF_WE1T   = OFF_NEG +  655360;     // 128 KB
static const size_t OFF_WP0T   = OFF_NEG +  786432;     // 128 KB
static const size_t OFF_WP1T   = OFF_NEG +  917504;     // 128 KB (ends at 1 MB)

// ---------------- CSR build ----------------
__global__ __launch_bounds__(256) void k_hist(const int* __restrict__ idx, int n, int* __restrict__ hist){
  int i = blockIdx.x*256 + threadIdx.x;
  if (i < n) atomicAdd(&hist[idx[i]], 1);
}

__global__ __launch_bounds__(256) void k_scan(const int* __restrict__ hist, int* __restrict__ start){
  __shared__ int part[256];
  int t = threadIdx.x;
  int v[8]; int s = 0;
#pragma unroll
  for (int j=0;j<8;j++){ v[j] = hist[t*8+j]; s += v[j]; }
  part[t] = s;
  __syncthreads();
  if (t == 0){
    int run = 0;
    for (int i=0;i<256;i++){ int tmp = part[i]; part[i] = run; run += tmp; }
  }
  __syncthreads();
  int run = part[t];
#pragma unroll
  for (int j=0;j<8;j++){ start[t*8+j] = run; run += v[j]; }
  if (t == 255) start[M_CL] = run;
}

__global__ __launch_bounds__(256) void k_scatter_pts(const int* __restrict__ assign, const int* __restrict__ start,
                                                     int* __restrict__ cur, int* __restrict__ out){
  int i = blockIdx.x*256 + threadIdx.x;
  if (i < N_PTS){
    int r = assign[i];
    int p = start[r] + atomicAdd(&cur[r], 1);
    out[p] = i;
  }
}

__global__ __launch_bounds__(256) void k_scatter_edges(const int* __restrict__ rows, const int* __restrict__ cols,
                                                       const float* __restrict__ vals, const int* __restrict__ start,
                                                       int* __restrict__ cur, int* __restrict__ scol,
                                                       float* __restrict__ sval){
  int e = blockIdx.x*256 + threadIdx.x;
  if (e < E_EDG){
    int r = rows[e];
    int p = start[r] + atomicAdd(&cur[r], 1);
    scol[p] = cols[e];
    sval[p] = vals[e];
  }
}

// ---------------- Xc = segsum(p * x), cnt = segsum(p) ----------------
__global__ __launch_bounds__(256) void k_cluster_agg(const float* __restrict__ x, const float* __restrict__ pv,
                                                     const int* __restrict__ sorted_pt, const int* __restrict__ start,
                                                     float* __restrict__ Xc, float* __restrict__ cnt){
  int m = blockIdx.x, t = threadIdx.x;
  int s0 = start[m], s1 = start[m+1];
  float a0 = 0.f, a1 = 0.f, c = 0.f;
  for (int p=s0;p<s1;p++){
    int row = sorted_pt[p];
    float w = pv[row];
    float2 xv = *reinterpret_cast<const float2*>(x + (size_t)row*IN_DIM + t*2);
    a0 = fmaf(w, xv.x, a0);
    a1 = fmaf(w, xv.y, a1);
    c += w;
  }
  *reinterpret_cast<float2*>(Xc + (size_t)m*IN_DIM + t*2) = make_float2(a0, a1);
  if (t == 0) cnt[m] = c;
}

// ---------------- weight transpose+convert: W[k][n] f32 -> Wt[n][k] bf16 ----------------
template<int K>
__global__ __launch_bounds__(256) void k_transpose_bf16(const float* __restrict__ W, u16* __restrict__ Wt){
  int o = blockIdx.x*256 + threadIdx.x;   // o = n*K + k
  int n = o / K, k = o % K;
  Wt[o] = f2bf(W[(size_t)k*HID + n]);
}

// ===================== unified wave-layer MFMA building blocks =====================
// Wave structure: wave w owns m-rows [w*16, w*16+16) of the block tile, ALL 256 n.
// Frags: A = weight rows (n = nf*16 + c), B = activation rows (m = w*16 + c),
// both lane layouts: elem k = lg*8+j. D: lane holds col m=c, rows n = nf*16+lg*4+r.
// Activations hand off between layers via LDS [64 m][256 n] bf16 (swizzled),
// written and read by the SAME wave -> no barriers needed (lgkmcnt ordering).

// LDS 8B-unit address for row ml, 8B-unit column kq (kq in [0,64))
__device__ __forceinline__ int lds_u(int ml, int kq){ return ml*64 + (kq ^ ((ml&7)<<1)); }

// one K=256 layer from LDS activations: acc[nf] += Wt-row-frags * lds-act
__device__ __forceinline__ void layer256(const u16* __restrict__ Wt, const u16* t_lds,
                                         int ml, int c, int lg, f32x4 acc[16]){
#pragma unroll
  for (int k0=0;k0<HID;k0+=32){
    int kq = (k0>>2) + lg*2;
    bf16x8 bfr = *reinterpret_cast<const bf16x8*>(&t_lds[lds_u(ml,kq)*4]);
#pragma unroll
    for (int nf=0;nf<16;nf++){
      bf16x8 afr = *reinterpret_cast<const bf16x8*>(Wt + (size_t)(nf*16+c)*HID + k0);
      acc[nf] = __builtin_amdgcn_mfma_f32_16x16x32_bf16(afr, bfr, acc[nf], 0,0,0);
    }
  }
}

// one K=512 layer from global f32 activations (depth-2 x prefetch)
__device__ __forceinline__ void layer512_global(const u16* __restrict__ Wt,
                                                const float* __restrict__ arow,  // row base + lg*8
                                                int c, int lg, f32x4 acc[16]){
  f32x4 s0a = *reinterpret_cast<const f32x4*>(arow);
  f32x4 s0b = *reinterpret_cast<const f32x4*>(arow+4);
  f32x4 s1a = *reinterpret_cast<const f32x4*>(arow+32);
  f32x4 s1b = *reinterpret_cast<const f32x4*>(arow+36);
#pragma unroll
  for (int k0=0;k0<IN_DIM;k0+=32){
    const int kn = (k0+64 < IN_DIM) ? k0+64 : 0;   // wrap: prefetch discarded on last iters
    f32x4 s2a = *reinterpret_cast<const f32x4*>(arow+kn);
    f32x4 s2b = *reinterpret_cast<const f32x4*>(arow+kn+4);
    bf16x8 bfr = cvt8(s0a, s0b);
#pragma unroll
    for (int nf=0;nf<16;nf++){
      bf16x8 afr = *reinterpret_cast<const bf16x8*>(Wt + (size_t)(nf*16+c)*IN_DIM + k0);
      acc[nf] = __builtin_amdgcn_mfma_f32_16x16x32_bf16(afr, bfr, acc[nf], 0,0,0);
    }
    s0a = s1a; s0b = s1b; s1a = s2a; s1b = s2b;
  }
}

__device__ __forceinline__ void zero16(f32x4 acc[16]){
#pragma unroll
  for (int i=0;i<16;i++){ acc[i].x=0.f; acc[i].y=0.f; acc[i].z=0.f; acc[i].w=0.f; }
}

// ---------------- fused target encoder (MFMA) + pos_sim accumulation ----------------
__global__ __launch_bounds__(256,3) void k_target_mfma(
    const float* __restrict__ x, const u16* __restrict__ Wt0t, const float* __restrict__ bt0,
    const u16* __restrict__ Wt1t, const float* __restrict__ bt1,
    const float* __restrict__ q, const int* __restrict__ assign,
    const float* __restrict__ pv, float* __restrict__ posacc){
  __shared__ u16 t_lds[64*256];      // 32 KB
  const int t  = threadIdx.x;
  const int w  = t >> 6;
  const int l  = t & 63;
  const int c  = l & 15;
  const int lg = l >> 4;
  const int ml = w*16 + c;
  const int gm = blockIdx.x*64 + ml;
  const int gmc = (gm < N_PTS) ? gm : (N_PTS-1);

  f32x4 acc[16];
  zero16(acc);

  // phase 1: t = x @ Wt0   (K=512)
  layer512_global(Wt0t, x + (size_t)gmc*IN_DIM + lg*8, c, lg, acc);

  // +bt0 -> LDS (bf16, swizzled)
#pragma unroll
  for (int nf=0;nf<16;nf++){
    f32x4 b = *reinterpret_cast<const f32x4*>(bt0 + nf*16 + lg*4);
    f32x4 v = acc[nf] + b;
    uint2 p; p.x = pk2(v.x, v.y); p.y = pk2(v.z, v.w);
    *reinterpret_cast<uint2*>(&t_lds[lds_u(ml, nf*4+lg)*4]) = p;
  }

  // phase 2: v = t @ Wt1   (K=256)
  zero16(acc);
  layer256(Wt1t, t_lds, ml, c, lg, acc);

  // epilogue: +bt1, ||v||, dot(v, q[assign]), atomic
  const int cl = assign[gmc];
  const float* qrow = q + (size_t)cl*HID + lg*4;
  float ss = 0.f, d = 0.f;
#pragma unroll
  for (int nf=0;nf<16;nf++){
    f32x4 b  = *reinterpret_cast<const f32x4*>(bt1 + nf*16 + lg*4);
    f32x4 qv = *reinterpret_cast<const f32x4*>(qrow + nf*16);
    f32x4 v  = acc[nf] + b;
    ss = fmaf(v.x,v.x, fmaf(v.y,v.y, fmaf(v.z,v.z, fmaf(v.w,v.w, ss))));
    d  = fmaf(v.x,qv.x, fmaf(v.y,qv.y, fmaf(v.z,qv.z, fmaf(v.w,qv.w, d))));
  }
  ss += __shfl_xor(ss, 16, 64); ss += __shfl_xor(ss, 32, 64);
  d  += __shfl_xor(d , 16, 64); d  += __shfl_xor(d , 32, 64);
  if (lg == 0 && gm < N_PTS){
    float inv = 1.0f / fmaxf(sqrtf(ss), 1e-12f);
    atomicAdd(&posacc[cl], pv[gm] * d * inv * 2.0f);   // * (1/TAU)
  }
}

// ---------------- fused M-scale chain: encoder(2) + projector(2) + both norms ----------------
// per row m: t0 = Xc@We0 + cnt*be0 ; hc = t0@We1 + cnt*be1 -> hn (normalized, global)
//            u = relu(hc@Wp0 + bp0) ; qp = u@Wp1 + bp1 -> q (normalized, global)
__global__ __launch_bounds__(256,3) void k_mchain(
    const float* __restrict__ Xc, const float* __restrict__ cnt,
    const u16* __restrict__ We0t, const float* __restrict__ be0,
    const u16* __restrict__ We1t, const float* __restrict__ be1,
    const u16* __restrict__ Wp0t, const float* __restrict__ bp0,
    const u16* __restrict__ Wp1t, const float* __restrict__ bp1,
    float* __restrict__ hn, float* __restrict__ q){
  __shared__ u16 t_lds[64*256];
  const int t  = threadIdx.x;
  const int w  = t >> 6;
  const int l  = t & 63;
  const int c  = l & 15;
  const int lg = l >> 4;
  const int ml = w*16 + c;
  const int gm = blockIdx.x*64 + ml;      // < 2048 always
  const float cv = cnt[gm];

  f32x4 acc[16];

  // L0: K=512 from global Xc
  zero16(acc);
  layer512_global(We0t, Xc + (size_t)gm*IN_DIM + lg*8, c, lg, acc);
#pragma unroll
  for (int nf=0;nf<16;nf++){
    f32x4 b = *reinterpret_cast<const f32x4*>(be0 + nf*16 + lg*4);
    f32x4 v = acc[nf];
    v.x = fmaf(cv, b.x, v.x); v.y = fmaf(cv, b.y, v.y);
    v.z = fmaf(cv, b.z, v.z); v.w = fmaf(cv, b.w, v.w);
    uint2 p; p.x = pk2(v.x, v.y); p.y = pk2(v.z, v.w);
    *reinterpret_cast<uint2*>(&t_lds[lds_u(ml, nf*4+lg)*4]) = p;
  }

  // L1: hc = t0 @ We1 + cv*be1
  zero16(acc);
  layer256(We1t, t_lds, ml, c, lg, acc);
  f32x4 hc[16];
  float ss = 0.f;
#pragma unroll
  for (int nf=0;nf<16;nf++){
    f32x4 b = *reinterpret_cast<const f32x4*>(be1 + nf*16 + lg*4);
    f32x4 v = acc[nf];
    v.x = fmaf(cv, b.x, v.x); v.y = fmaf(cv, b.y, v.y);
    v.z = fmaf(cv, b.z, v.z); v.w = fmaf(cv, b.w, v.w);
    hc[nf] = v;
    ss = fmaf(v.x,v.x, fmaf(v.y,v.y, fmaf(v.z,v.z, fmaf(v.w,v.w, ss))));
  }
  ss += __shfl_xor(ss, 16, 64); ss += __shfl_xor(ss, 32, 64);
  {
    float inv = 1.0f / fmaxf(sqrtf(ss), 1e-12f);
    float* hrow = hn + (size_t)gm*HID + lg*4;
#pragma unroll
    for (int nf=0;nf<16;nf++){
      f32x4 v = hc[nf];
      f32x4 o; o.x = v.x*inv; o.y = v.y*inv; o.z = v.z*inv; o.w = v.w*inv;
      *reinterpret_cast<f32x4*>(hrow + nf*16) = o;
      uint2 p; p.x = pk2(v.x, v.y); p.y = pk2(v.z, v.w);
      *reinterpret_cast<uint2*>(&t_lds[lds_u(ml, nf*4+lg)*4]) = p;   // hc -> LDS for L2
    }
  }

  // L2: u = relu(hc @ Wp0 + bp0)
  zero16(acc);
  layer256(Wp0t, t_lds, ml, c, lg, acc);
#pragma unroll
  for (int nf=0;nf<16;nf++){
    f32x4 b = *reinterpret_cast<const f32x4*>(bp0 + nf*16 + lg*4);
    f32x4 v = acc[nf] + b;
    v.x = fmaxf(v.x, 0.f); v.y = fmaxf(v.y, 0.f);
    v.z = fmaxf(v.z, 0.f); v.w = fmaxf(v.w, 0.f);
    uint2 p; p.x = pk2(v.x, v.y); p.y = pk2(v.z, v.w);
    *reinterpret_cast<uint2*>(&t_lds[lds_u(ml, nf*4+lg)*4]) = p;
  }

  // L3: qp = u @ Wp1 + bp1 -> normalize -> q
  zero16(acc);
  layer256(Wp1t, t_lds, ml, c, lg, acc);
  ss = 0.f;
#pragma unroll
  for (int nf=0;nf<16;nf++){
    f32x4 b = *reinterpret_cast<const f32x4*>(bp1 + nf*16 + lg*4);
    acc[nf] = acc[nf] + b;
    f32x4 v = acc[nf];
    ss = fmaf(v.x,v.x, fmaf(v.y,v.y, fmaf(v.z,v.z, fmaf(v.w,v.w, ss))));
  }
  ss += __shfl_xor(ss, 16, 64); ss += __shfl_xor(ss, 32, 64);
  {
    float inv = 1.0f / fmaxf(sqrtf(ss), 1e-12f);
    float* qrow = q + (size_t)gm*HID + lg*4;
#pragma unroll
    for (int nf=0;nf<16;nf++){
      f32x4 v = acc[nf];
      f32x4 o; o.x = v.x*inv; o.y = v.y*inv; o.z = v.z*inv; o.w = v.w*inv;
      *reinterpret_cast<f32x4*>(qrow + nf*16) = o;
    }
  }
}

// ---------------- neg = exp(hn @ hn^T / TAU), negsum = rowsum ----------------
__global__ __launch_bounds__(256) void k_neg(const float* __restrict__ hn, float* __restrict__ neg,
                                             float* __restrict__ negsum){
  __shared__ __align__(16) float at[64*64];
  __shared__ __align__(16) float bt[64*64];
  const int t  = threadIdx.x;
  const int ty = t >> 4, tx = t & 15;
  const int i0 = blockIdx.y*64, j0 = blockIdx.x*64;
  const int r  = t & 63, kq = t >> 6;
  float acc[4][4] = {};
  for (int kc=0;kc<4;kc++){
    int k0 = kc*64;
    float4 av[4], bv[4];
#pragma unroll
    for (int j=0;j<4;j++){
      int kb = kq*16 + j*4;
      av[j] = *reinterpret_cast<const float4*>(hn + (size_t)(i0+r)*HID + k0 + kb);
      bv[j] = *reinterpret_cast<const float4*>(hn + (size_t)(j0+r)*HID + k0 + kb);
    }
    __syncthreads();
#pragma unroll
    for (int j=0;j<4;j++){
      int kb = kq*16 + j*4;
      at[(kb+0)*64+r]=av[j].x; at[(kb+1)*64+r]=av[j].y; at[(kb+2)*64+r]=av[j].z; at[(kb+3)*64+r]=av[j].w;
      bt[(kb+0)*64+r]=bv[j].x; bt[(kb+1)*64+r]=bv[j].y; bt[(kb+2)*64+r]=bv[j].z; bt[(kb+3)*64+r]=bv[j].w;
    }
    __syncthreads();
#pragma unroll 8
    for (int k=0;k<64;k++){
      float4 a = *reinterpret_cast<const float4*>(&at[k*64 + ty*4]);
      float4 b = *reinterpret_cast<const float4*>(&bt[k*64 + tx*4]);
      float aa[4] = {a.x,a.y,a.z,a.w}, bb[4] = {b.x,b.y,b.z,b.w};
#pragma unroll
      for (int ii=0;ii<4;ii++)
#pragma unroll
        for (int jj=0;jj<4;jj++) acc[ii][jj] = fmaf(aa[ii], bb[jj], acc[ii][jj]);
    }
  }
#pragma unroll
  for (int ii=0;ii<4;ii++){
    float4 e;
    e.x = __expf(acc[ii][0]*2.0f);
    e.y = __expf(acc[ii][1]*2.0f);
    e.z = __expf(acc[ii][2]*2.0f);
    e.w = __expf(acc[ii][3]*2.0f);
    int row = i0 + ty*4 + ii;
    *reinterpret_cast<float4*>(neg + (size_t)row*M_CL + j0 + tx*4) = e;
    float rs = e.x+e.y+e.z+e.w;
#pragma unroll
    for (int off=8;off;off>>=1) rs += __shfl_xor(rs, off, 16);
    if (tx == 0) atomicAdd(&negsum[row], rs);
  }
}

// ---------------- loss ----------------
__global__ __launch_bounds__(256) void k_loss(const float* __restrict__ neg, const float* __restrict__ negsum,
                                              const float* __restrict__ posacc, const int* __restrict__ start,
                                              const int* __restrict__ scol, const float* __restrict__ sval,
                                              double* __restrict__ loss){
  const int i = blockIdx.x, t = threadIdx.x;
  float ps[8] = {};
  const int s0 = start[i], s1 = start[i+1];
  for (int e=s0;e<s1;e++){
    int c = scol[e];
    float v = sval[e];
    const float* row = neg + (size_t)c*M_CL + t;
#pragma unroll
    for (int jj=0;jj<8;jj++) ps[jj] = fmaf(v, row[jj*256], ps[jj]);
  }
  float pos = __expf(posacc[i]);
  float part = 0.f;
#pragma unroll
  for (int jj=0;jj<8;jj++){
    int j = t + jj*256;
    part += __logf(pos + negsum[j]) - __logf(pos + ps[jj]);  // LAMDA = 1
  }
#pragma unroll
  for (int off=32;off;off>>=1) part += __shfl_xor(part, off, 64);
  __shared__ float wsum[4];
  if ((t&63) == 0) wsum[t>>6] = part;
  __syncthreads();
  if (t == 0){
    double s = (double)wsum[0] + (double)wsum[1] + (double)wsum[2] + (double)wsum[3];
    atomicAdd(loss, s);
  }
}

__global__ void k_finalize(const double* __restrict__ loss, float* __restrict__ out){
  if (threadIdx.x == 0 && blockIdx.x == 0)
    out[0] = (float)(loss[0] / ((double)M_CL * (double)M_CL));
}

// ---------------- launch ----------------
extern "C" void kernel_launch(void* const* d_in, const int* in_sizes, int n_in,
                              void* d_out, int out_size, void* d_ws, size_t ws_size,
                              hipStream_t stream){
  const float* x    = (const float*)d_in[0];
  const float* We0  = (const float*)d_in[1];
  const float* be0  = (const float*)d_in[2];
  const float* We1  = (const float*)d_in[3];
  const float* be1  = (const float*)d_in[4];
  const float* Wt0  = (const float*)d_in[5];
  const float* bt0  = (const float*)d_in[6];
  const float* Wt1  = (const float*)d_in[7];
  const float* bt1  = (const float*)d_in[8];
  const float* Wp0  = (const float*)d_in[9];
  const float* bp0  = (const float*)d_in[10];
  const float* Wp1  = (const float*)d_in[11];
  const float* bp1  = (const float*)d_in[12];
  const float* pv   = (const float*)d_in[13];
  const float* cgv  = (const float*)d_in[14];
  const int*   pas  = (const int*)d_in[15];
  const int*   cgr  = (const int*)d_in[16];
  const int*   cgc  = (const int*)d_in[17];

  char* ws = (char*)d_ws;
  float*  posacc  = (float*)(ws + OFF_POSACC);
  float*  negsum  = (float*)(ws + OFF_NEGSUM);
  int*    hist_p  = (int*)  (ws + OFF_HISTP);
  int*    cur_p   = (int*)  (ws + OFF_CURP);
  int*    hist_e  = (int*)  (ws + OFF_HISTE);
  int*    cur_e   = (int*)  (ws + OFF_CURE);
  double* lossd   = (double*)(ws + OFF_LOSS);
  int*    start_p = (int*)  (ws + OFF_STARTP);
  int*    start_e = (int*)  (ws + OFF_STARTE);
  int*    sortpt  = (int*)  (ws + OFF_SORTPT);
  int*    scol    = (int*)  (ws + OFF_SCOL);
  float*  sval    = (float*)(ws + OFF_SVAL);
  float*  cnt     = (float*)(ws + OFF_CNT);
  float*  Xc      = (float*)(ws + OFF_XC);
  float*  qb      = (float*)(ws + OFF_Q);
  float*  hn      = (float*)(ws + OFF_HN);
  float*  negbuf  = (float*)(ws + OFF_NEG);
  u16*    Wt0t    = (u16*)  (ws + OFF_WT0T);
  u16*    Wt1t    = (u16*)  (ws + OFF_WT1T);
  u16*    We0t    = (u16*)  (ws + OFF_WE0T);
  u16*    We1t    = (u16*)  (ws + OFF_WE1T);
  u16*    Wp0t    = (u16*)  (ws + OFF_WP0T);
  u16*    Wp1t    = (u16*)  (ws + OFF_WP1T);

  hipMemsetAsync(ws, 0, ZERO_BYTES, stream);

  k_hist<<<(N_PTS+255)/256, 256, 0, stream>>>(pas, N_PTS, hist_p);
  k_hist<<<(E_EDG+255)/256, 256, 0, stream>>>(cgr, E_EDG, hist_e);
  k_scan<<<1, 256, 0, stream>>>(hist_p, start_p);
  k_scan<<<1, 256, 0, stream>>>(hist_e, start_e);
  k_scatter_pts<<<(N_PTS+255)/256, 256, 0, stream>>>(pas, start_p, cur_p, sortpt);
  k_scatter_edges<<<(E_EDG+255)/256, 256, 0, stream>>>(cgr, cgc, cgv, start_e, cur_e, scol, sval);

  k_transpose_bf16<IN_DIM><<<IN_DIM, 256, 0, stream>>>(Wt0, Wt0t);
  k_transpose_bf16<HID  ><<<HID,    256, 0, stream>>>(Wt1, Wt1t);
  k_transpose_bf16<IN_DIM><<<IN_DIM, 256, 0, stream>>>(We0, We0t);
  k_transpose_bf16<HID  ><<<HID,    256, 0, stream>>>(We1, We1t);
  k_transpose_bf16<HID  ><<<HID,    256, 0, stream>>>(Wp0, Wp0t);
  k_transpose_bf16<HID  ><<<HID,    256, 0, stream>>>(Wp1, Wp1t);

  k_cluster_agg<<<M_CL, 256, 0, stream>>>(x, pv, sortpt, start_p, Xc, cnt);

  k_mchain<<<M_CL/64, 256, 0, stream>>>(Xc, cnt, We0t, be0, We1t, be1, Wp0t, bp0, Wp1t, bp1, hn, qb);

  k_target_mfma<<<(N_PTS+63)/64, 256, 0, stream>>>(x, Wt0t, bt0, Wt1t, bt1, qb, pas, pv, posacc);

  dim3 g2(M_CL/64, M_CL/64);
  k_neg<<<g2, 256, 0, stream>>>(hn, negbuf, negsum);

  k_loss<<<M_CL, 256, 0, stream>>>(negbuf, negsum, posacc, start_e, scol, sval, lossd);
  k_finalize<<<1, 64, 0, stream>>>(lossd, (float*)d_out);
}

// Round 4
// 377.770 us; speedup vs baseline: 1.8925x; 1.8925x over previous
//
#include <hip/hip_runtime.h>
#include <hip/hip_bf16.h>
#include <math.h>

#define N_PTS  100000
#define M_CL   2048
#define E_EDG  65536
#define IN_DIM 512
#define HID    256
// TAU = 0.5 -> 1/TAU = 2.0 ; LAMDA = 1.0 (folded)

typedef unsigned short u16;
typedef __attribute__((ext_vector_type(8))) short bf16x8;
typedef __attribute__((ext_vector_type(4))) float f32x4;

__device__ __forceinline__ u16 f2bf(float f){
  __hip_bfloat16 h = __float2bfloat16(f);
  return *reinterpret_cast<u16*>(&h);
}
__device__ __forceinline__ unsigned pk2(float a, float b){
  return (unsigned)f2bf(a) | ((unsigned)f2bf(b) << 16);
}
__device__ __forceinline__ bf16x8 cvt8(f32x4 lo, f32x4 hi){
  bf16x8 r;
  r[0]=(short)f2bf(lo.x); r[1]=(short)f2bf(lo.y); r[2]=(short)f2bf(lo.z); r[3]=(short)f2bf(lo.w);
  r[4]=(short)f2bf(hi.x); r[5]=(short)f2bf(hi.y); r[6]=(short)f2bf(hi.z); r[7]=(short)f2bf(hi.w);
  return r;
}
// async global->LDS, 16B per lane. dest must be wave-uniform base + lane*16.
__device__ __forceinline__ void glds16(const u16* g, u16* l){
  __builtin_amdgcn_global_load_lds(
      (const __attribute__((address_space(1))) unsigned int*)(g),
      (__attribute__((address_space(3))) unsigned int*)(l), 16, 0, 0);
}

// ---------------- workspace layout (bytes) ----------------
static const size_t OFF_POSACC = 0;              // M floats
static const size_t OFF_NEGSUM = 8192;           // M floats
static const size_t OFF_HISTP  = 16384;          // M ints
static const size_t OFF_CURP   = 24576;          // M ints
static const size_t OFF_HISTE  = 32768;          // M ints
static const size_t OFF_CURE   = 40960;          // M ints
static const size_t OFF_LOSS   = 49152;          // 1 double
static const size_t ZERO_BYTES = 49408;
static const size_t OFF_STARTP = 49664;          // M+1 ints
static const size_t OFF_STARTE = 58112;          // M+1 ints
static const size_t OFF_SORTPT = 66560;          // N ints
static const size_t OFF_SCOL   = 466688;         // E ints
static const size_t OFF_SVAL   = 728832;         // E floats
static const size_t OFF_CNT    = 990976;         // M floats
static const size_t OFF_XC     = 999168;         // M*512 floats (ends 5193472)
static const size_t OFF_HC     = 5193472;        // M*256 floats
static const size_t OFF_T0     = 7290624;        // M*256 floats
static const size_t OFF_Q      = 9387776;        // M*256 floats
static const size_t OFF_HN     = 11484928;       // M*256 floats
static const size_t OFF_NEG    = 13582080;       // M*M floats = 16 MB
// bf16-transposed weights alias the NEG region: consumed by k_target_mfma
// (before k_neg writes negbuf; stream-ordered).
static const size_t OFF_WT0T   = OFF_NEG;               // 256*512*2 = 256 KB
static const size_t OFF_WT1T   = OFF_NEG + 262144;      // 128 KB

// ---------------- CSR build ----------------
__global__ __launch_bounds__(256) void k_hist(const int* __restrict__ idx, int n, int* __restrict__ hist){
  int i = blockIdx.x*256 + threadIdx.x;
  if (i < n) atomicAdd(&hist[idx[i]], 1);
}

__global__ __launch_bounds__(256) void k_scan(const int* __restrict__ hist, int* __restrict__ start){
  __shared__ int part[256];
  int t = threadIdx.x;
  int v[8]; int s = 0;
#pragma unroll
  for (int j=0;j<8;j++){ v[j] = hist[t*8+j]; s += v[j]; }
  part[t] = s;
  __syncthreads();
  if (t == 0){
    int run = 0;
    for (int i=0;i<256;i++){ int tmp = part[i]; part[i] = run; run += tmp; }
  }
  __syncthreads();
  int run = part[t];
#pragma unroll
  for (int j=0;j<8;j++){ start[t*8+j] = run; run += v[j]; }
  if (t == 255) start[M_CL] = run;
}

__global__ __launch_bounds__(256) void k_scatter_pts(const int* __restrict__ assign, const int* __restrict__ start,
                                                     int* __restrict__ cur, int* __restrict__ out){
  int i = blockIdx.x*256 + threadIdx.x;
  if (i < N_PTS){
    int r = assign[i];
    int p = start[r] + atomicAdd(&cur[r], 1);
    out[p] = i;
  }
}

__global__ __launch_bounds__(256) void k_scatter_edges(const int* __restrict__ rows, const int* __restrict__ cols,
                                                       const float* __restrict__ vals, const int* __restrict__ start,
                                                       int* __restrict__ cur, int* __restrict__ scol,
                                                       float* __restrict__ sval){
  int e = blockIdx.x*256 + threadIdx.x;
  if (e < E_EDG){
    int r = rows[e];
    int p = start[r] + atomicAdd(&cur[r], 1);
    scol[p] = cols[e];
    sval[p] = vals[e];
  }
}

// ---------------- Xc = segsum(p * x), cnt = segsum(p) ----------------
__global__ __launch_bounds__(256) void k_cluster_agg(const float* __restrict__ x, const float* __restrict__ pv,
                                                     const int* __restrict__ sorted_pt, const int* __restrict__ start,
                                                     float* __restrict__ Xc, float* __restrict__ cnt){
  int m = blockIdx.x, t = threadIdx.x;
  int s0 = start[m], s1 = start[m+1];
  float a0 = 0.f, a1 = 0.f, c = 0.f;
  for (int p=s0;p<s1;p++){
    int row = sorted_pt[p];
    float w = pv[row];
    float2 xv = *reinterpret_cast<const float2*>(x + (size_t)row*IN_DIM + t*2);
    a0 = fmaf(w, xv.x, a0);
    a1 = fmaf(w, xv.y, a1);
    c += w;
  }
  *reinterpret_cast<float2*>(Xc + (size_t)m*IN_DIM + t*2) = make_float2(a0, a1);
  if (t == 0) cnt[m] = c;
}

// ---------------- small GEMM (M-scale chains) ----------------
template<int K, int ROWS, bool RELU, bool SCALED>
__global__ __launch_bounds__(256) void k_gemm_small(const float* __restrict__ A, const float* __restrict__ W,
                                                    const float* __restrict__ bias, const float* __restrict__ scale,
                                                    float* __restrict__ out){
  __shared__ __align__(16) float a_sh[ROWS][K];
  int rb = blockIdx.x*ROWS, t = threadIdx.x;
  for (int i=t; i<ROWS*(K/4); i+=256){
    int r = i/(K/4), k4 = i%(K/4);
    reinterpret_cast<float4*>(a_sh[r])[k4] = reinterpret_cast<const float4*>(A + (size_t)(rb+r)*K)[k4];
  }
  __syncthreads();
  float acc[ROWS];
#pragma unroll
  for (int r=0;r<ROWS;r++) acc[r] = 0.f;
#pragma unroll 2
  for (int k=0;k<K;k+=4){
    float w0 = W[(size_t)(k+0)*HID + t];
    float w1 = W[(size_t)(k+1)*HID + t];
    float w2 = W[(size_t)(k+2)*HID + t];
    float w3 = W[(size_t)(k+3)*HID + t];
#pragma unroll
    for (int r=0;r<ROWS;r++){
      float4 av = *reinterpret_cast<const float4*>(&a_sh[r][k]);
      acc[r] = fmaf(av.x, w0, acc[r]);
      acc[r] = fmaf(av.y, w1, acc[r]);
      acc[r] = fmaf(av.z, w2, acc[r]);
      acc[r] = fmaf(av.w, w3, acc[r]);
    }
  }
  float b = bias[t];
#pragma unroll
  for (int r=0;r<ROWS;r++){
    float s = SCALED ? scale[rb+r] : 1.0f;
    float v = acc[r] + s*b;
    if (RELU) v = fmaxf(v, 0.0f);
    out[(size_t)(rb+r)*HID + t] = v;
  }
}

// ---------------- row L2-normalize ----------------
__global__ __launch_bounds__(256) void k_norm_rows(const float* __restrict__ in, float* __restrict__ out){
  int r = blockIdx.x, t = threadIdx.x;
  float v = in[(size_t)r*HID + t];
  float ss = v*v;
#pragma unroll
  for (int off=32;off;off>>=1) ss += __shfl_xor(ss, off, 64);
  __shared__ float wsum[4];
  if ((t&63) == 0) wsum[t>>6] = ss;
  __syncthreads();
  float tot = wsum[0]+wsum[1]+wsum[2]+wsum[3];
  float inv = 1.0f / fmaxf(sqrtf(tot), 1e-12f);
  out[(size_t)r*HID + t] = v*inv;
}

// ---------------- weight transpose+convert: W[k][n] f32 -> Wt[n][k] bf16 ----------------
template<int K>
__global__ __launch_bounds__(256) void k_transpose_bf16(const float* __restrict__ W, u16* __restrict__ Wt){
  int o = blockIdx.x*256 + threadIdx.x;   // o = n*K + k
  int n = o / K, k = o % K;
  Wt[o] = f2bf(W[(size_t)k*HID + n]);
}

// ---------------- fused target encoder (m97-style block GEMM) ----------------
// Block: 64 m x 256 n, 256 threads = 4 waves; wave w owns 64m x [w*64, w*64+64)n.
// K-slabs of 32, double-buffered. Weights staged via global_load_lds (16B),
// source pre-swizzled so ds_read_b128 frags are ~2-way conflict only.
// x reg-staged f32->bf16 into swizzled xs slab. Phase-1 result (t = x@Wt0+bt0)
// round-trips a 32KB act tile (bf16, XOR-swizzled); phase 2: v = t@Wt1.
// Epilogue: +bt1, row L2-norm, dot with q[assign], one atomic per row.
__global__ __launch_bounds__(256,2) void k_target_mfma(
    const float* __restrict__ x, const u16* __restrict__ Wt0t, const float* __restrict__ bt0,
    const u16* __restrict__ Wt1t, const float* __restrict__ bt1,
    const float* __restrict__ q, const int* __restrict__ assign,
    const float* __restrict__ pv, float* __restrict__ posacc){
  __shared__ u16 ws[2*8192];        // 2 x [256 n][32 k] bf16 = 32 KB
  __shared__ u16 act[16384];        // [64 m][256 n] bf16 = 32 KB; first 2x2048 doubles as xs dbuf
  __shared__ float red[2][4][4][16];
  u16* xs = act;                    // xs slab: [64 m][32 k] bf16 (2048 u16), dbuf

  const int t  = threadIdx.x;
  const int w  = t >> 6;            // wave = n-slab index
  const int l  = t & 63;
  const int c  = l & 15;
  const int lg = l >> 4;
  const int gm0 = blockIdx.x * 64;

  // x staging mapping: thread -> (row, 8-float unit)
  const int s_row = t >> 2;         // 0..63
  const int s_u   = t & 3;
  const int sx_g  = gm0 + s_row;
  const float* xsrc = x + (size_t)((sx_g < N_PTS) ? sx_g : (N_PTS-1))*IN_DIM + s_u*8;
  const int sx_off = (s_row*4 + (s_u ^ ((s_row>>1)&3)))*8;   // u16 offset in xs slab (swizzled)

  f32x4 acc[4][4];
#pragma unroll
  for (int i=0;i<4;i++)
#pragma unroll
    for (int j=0;j<4;j++){ acc[i][j].x=0.f; acc[i][j].y=0.f; acc[i][j].z=0.f; acc[i][j].w=0.f; }

  // ---- staging helpers ----
  // weights: wave w stages rows [w*64, w*64+64), 4 instrs x 1KB, pre-swizzled source
  #define STAGE_W(Wt, K, k0, buf) do { \
    _Pragma("unroll") \
    for (int i_=0;i_<4;i_++){ \
      int row_ = w*64 + i_*16 + (l>>2); \
      int ug_  = (l&3) ^ ((row_>>1)&3); \
      glds16((Wt) + (size_t)row_*(K) + (k0) + ug_*8, \
             ws + (buf)*8192 + (w*64 + i_*16)*32 + l*8); \
    } } while(0)

  #define STAGE_X(k0, buf) do { \
    f32x4 a_ = *reinterpret_cast<const f32x4*>(xsrc + (k0)); \
    f32x4 b_ = *reinterpret_cast<const f32x4*>(xsrc + (k0) + 4); \
    *reinterpret_cast<bf16x8*>(xs + (buf)*2048 + sx_off) = cvt8(a_, b_); \
  } while(0)

  const int su = lg ^ ((c>>1)&3);   // swizzled 16B-unit index for frag reads

  // ================= phase 1: t = x @ Wt0  (K=512, 16 slabs) =================
  STAGE_W(Wt0t, IN_DIM, 0, 0);
  STAGE_X(0, 0);
  __syncthreads();
#pragma unroll
  for (int ks=0; ks<16; ks++){
    int buf = ks & 1;
    if (ks < 15){ STAGE_W(Wt0t, IN_DIM, (ks+1)*32, buf^1); STAGE_X((ks+1)*32, buf^1); }
    bf16x8 bfr[4];
#pragma unroll
    for (int mf=0; mf<4; mf++)
      bfr[mf] = *reinterpret_cast<const bf16x8*>(xs + buf*2048 + ((mf*16+c)*4 + su)*8);
#pragma unroll
    for (int nf=0; nf<4; nf++){
      bf16x8 afr = *reinterpret_cast<const bf16x8*>(ws + buf*8192 + ((w*64+nf*16+c)*4 + su)*8);
#pragma unroll
      for (int mf=0; mf<4; mf++)
        acc[mf][nf] = __builtin_amdgcn_mfma_f32_16x16x32_bf16(afr, bfr[mf], acc[mf][nf], 0,0,0);
    }
    __syncthreads();
  }

  // ---- epilogue-1: acc + bt0 -> act (bf16, unit-swizzled u ^ (m&7)) ----
#pragma unroll
  for (int nf=0; nf<4; nf++){
    f32x4 bias = *reinterpret_cast<const f32x4*>(bt0 + w*64 + nf*16 + lg*4);
#pragma unroll
    for (int mf=0; mf<4; mf++){
      int m = mf*16 + c;
      f32x4 v = acc[mf][nf] + bias;
      uint2 p; p.x = pk2(v.x, v.y); p.y = pk2(v.z, v.w);
      int u = (w*8 + nf*2 + (lg>>1)) ^ (c&7);
      *reinterpret_cast<uint2*>(act + (m*32 + u)*8 + (lg&1)*4) = p;
    }
  }
#pragma unroll
  for (int i=0;i<4;i++)
#pragma unroll
    for (int j=0;j<4;j++){ acc[i][j].x=0.f; acc[i][j].y=0.f; acc[i][j].z=0.f; acc[i][j].w=0.f; }
  STAGE_W(Wt1t, HID, 0, 0);
  __syncthreads();

  // ================= phase 2: v = t @ Wt1  (K=256, 8 slabs) =================
#pragma unroll
  for (int ks=0; ks<8; ks++){
    int buf = ks & 1;
    if (ks < 7) STAGE_W(Wt1t, HID, (ks+1)*32, buf^1);
    bf16x8 bfr[4];
#pragma unroll
    for (int mf=0; mf<4; mf++){
      int m = mf*16 + c;
      int u = (ks*4 + lg) ^ (c&7);
      bfr[mf] = *reinterpret_cast<const bf16x8*>(act + (m*32 + u)*8);
    }
#pragma unroll
    for (int nf=0; nf<4; nf++){
      bf16x8 afr = *reinterpret_cast<const bf16x8*>(ws + buf*8192 + ((w*64+nf*16+c)*4 + su)*8);
#pragma unroll
      for (int mf=0; mf<4; mf++)
        acc[mf][nf] = __builtin_amdgcn_mfma_f32_16x16x32_bf16(afr, bfr[mf], acc[mf][nf], 0,0,0);
    }
    __syncthreads();
  }

  // ---- epilogue-2: +bt1, partial ||v|| and v.q per (mf,c), cross-wave combine ----
#pragma unroll
  for (int mf=0; mf<4; mf++){
    int gm = gm0 + mf*16 + c;
    int cl = assign[(gm < N_PTS) ? gm : (N_PTS-1)];
    const float* qrow = q + (size_t)cl*HID + w*64 + lg*4;
    float ss = 0.f, d = 0.f;
#pragma unroll
    for (int nf=0; nf<4; nf++){
      f32x4 b  = *reinterpret_cast<const f32x4*>(bt1 + w*64 + nf*16 + lg*4);
      f32x4 qv = *reinterpret_cast<const f32x4*>(qrow + nf*16);
      f32x4 v  = acc[mf][nf] + b;
      ss = fmaf(v.x,v.x, fmaf(v.y,v.y, fmaf(v.z,v.z, fmaf(v.w,v.w, ss))));
      d  = fmaf(v.x,qv.x, fmaf(v.y,qv.y, fmaf(v.z,qv.z, fmaf(v.w,qv.w, d))));
    }
    ss += __shfl_xor(ss, 16, 64); ss += __shfl_xor(ss, 32, 64);
    d  += __shfl_xor(d , 16, 64); d  += __shfl_xor(d , 32, 64);
    if (lg == 0){ red[0][w][mf][c] = ss; red[1][w][mf][c] = d; }
  }
  __syncthreads();
  if (t < 64){
    int gm = gm0 + t;
    if (gm < N_PTS){
      int mf = t>>4, cc = t&15;
      float ss = red[0][0][mf][cc]+red[0][1][mf][cc]+red[0][2][mf][cc]+red[0][3][mf][cc];
      float d  = red[1][0][mf][cc]+red[1][1][mf][cc]+red[1][2][mf][cc]+red[1][3][mf][cc];
      float inv = 1.0f / fmaxf(sqrtf(ss), 1e-12f);
      atomicAdd(&posacc[assign[gm]], pv[gm] * d * inv * 2.0f);   // * (1/TAU)
    }
  }
  #undef STAGE_W
  #undef STAGE_X
}

// ---------------- neg = exp(hn @ hn^T / TAU), negsum = rowsum ----------------
__global__ __launch_bounds__(256) void k_neg(const float* __restrict__ hn, float* __restrict__ neg,
                                             float* __restrict__ negsum){
  __shared__ __align__(16) float at[64*64];
  __shared__ __align__(16) float bt[64*64];
  const int t  = threadIdx.x;
  const int ty = t >> 4, tx = t & 15;
  const int i0 = blockIdx.y*64, j0 = blockIdx.x*64;
  const int r  = t & 63, kq = t >> 6;
  float acc[4][4] = {};
  for (int kc=0;kc<4;kc++){
    int k0 = kc*64;
    float4 av[4], bv[4];
#pragma unroll
    for (int j=0;j<4;j++){
      int kb = kq*16 + j*4;
      av[j] = *reinterpret_cast<const float4*>(hn + (size_t)(i0+r)*HID + k0 + kb);
      bv[j] = *reinterpret_cast<const float4*>(hn + (size_t)(j0+r)*HID + k0 + kb);
    }
    __syncthreads();
#pragma unroll
    for (int j=0;j<4;j++){
      int kb = kq*16 + j*4;
      at[(kb+0)*64+r]=av[j].x; at[(kb+1)*64+r]=av[j].y; at[(kb+2)*64+r]=av[j].z; at[(kb+3)*64+r]=av[j].w;
      bt[(kb+0)*64+r]=bv[j].x; bt[(kb+1)*64+r]=bv[j].y; bt[(kb+2)*64+r]=bv[j].z; bt[(kb+3)*64+r]=bv[j].w;
    }
    __syncthreads();
#pragma unroll 8
    for (int k=0;k<64;k++){
      float4 a = *reinterpret_cast<const float4*>(&at[k*64 + ty*4]);
      float4 b = *reinterpret_cast<const float4*>(&bt[k*64 + tx*4]);
      float aa[4] = {a.x,a.y,a.z,a.w}, bb[4] = {b.x,b.y,b.z,b.w};
#pragma unroll
      for (int ii=0;ii<4;ii++)
#pragma unroll
        for (int jj=0;jj<4;jj++) acc[ii][jj] = fmaf(aa[ii], bb[jj], acc[ii][jj]);
    }
  }
#pragma unroll
  for (int ii=0;ii<4;ii++){
    float4 e;
    e.x = __expf(acc[ii][0]*2.0f);
    e.y = __expf(acc[ii][1]*2.0f);
    e.z = __expf(acc[ii][2]*2.0f);
    e.w = __expf(acc[ii][3]*2.0f);
    int row = i0 + ty*4 + ii;
    *reinterpret_cast<float4*>(neg + (size_t)row*M_CL + j0 + tx*4) = e;
    float rs = e.x+e.y+e.z+e.w;
#pragma unroll
    for (int off=8;off;off>>=1) rs += __shfl_xor(rs, off, 16);
    if (tx == 0) atomicAdd(&negsum[row], rs);
  }
}

// ---------------- loss ----------------
__global__ __launch_bounds__(256) void k_loss(const float* __restrict__ neg, const float* __restrict__ negsum,
                                              const float* __restrict__ posacc, const int* __restrict__ start,
                                              const int* __restrict__ scol, const float* __restrict__ sval,
                                              double* __restrict__ loss){
  const int i = blockIdx.x, t = threadIdx.x;
  float ps[8] = {};
  const int s0 = start[i], s1 = start[i+1];
  for (int e=s0;e<s1;e++){
    int c = scol[e];
    float v = sval[e];
    const float* row = neg + (size_t)c*M_CL + t;
#pragma unroll
    for (int jj=0;jj<8;jj++) ps[jj] = fmaf(v, row[jj*256], ps[jj]);
  }
  float pos = __expf(posacc[i]);
  float part = 0.f;
#pragma unroll
  for (int jj=0;jj<8;jj++){
    int j = t + jj*256;
    part += __logf(pos + negsum[j]) - __logf(pos + ps[jj]);  // LAMDA = 1
  }
#pragma unroll
  for (int off=32;off;off>>=1) part += __shfl_xor(part, off, 64);
  __shared__ float wsum[4];
  if ((t&63) == 0) wsum[t>>6] = part;
  __syncthreads();
  if (t == 0){
    double s = (double)wsum[0] + (double)wsum[1] + (double)wsum[2] + (double)wsum[3];
    atomicAdd(loss, s);
  }
}

__global__ void k_finalize(const double* __restrict__ loss, float* __restrict__ out){
  if (threadIdx.x == 0 && blockIdx.x == 0)
    out[0] = (float)(loss[0] / ((double)M_CL * (double)M_CL));
}

// ---------------- launch ----------------
extern "C" void kernel_launch(void* const* d_in, const int* in_sizes, int n_in,
                              void* d_out, int out_size, void* d_ws, size_t ws_size,
                              hipStream_t stream){
  const float* x    = (const float*)d_in[0];
  const float* We0  = (const float*)d_in[1];
  const float* be0  = (const float*)d_in[2];
  const float* We1  = (const float*)d_in[3];
  const float* be1  = (const float*)d_in[4];
  const float* Wt0  = (const float*)d_in[5];
  const float* bt0  = (const float*)d_in[6];
  const float* Wt1  = (const float*)d_in[7];
  const float* bt1  = (const float*)d_in[8];
  const float* Wp0  = (const float*)d_in[9];
  const float* bp0  = (const float*)d_in[10];
  const float* Wp1  = (const float*)d_in[11];
  const float* bp1  = (const float*)d_in[12];
  const float* pv   = (const float*)d_in[13];
  const float* cgv  = (const float*)d_in[14];
  const int*   pas  = (const int*)d_in[15];
  const int*   cgr  = (const int*)d_in[16];
  const int*   cgc  = (const int*)d_in[17];

  char* ws = (char*)d_ws;
  float*  posacc  = (float*)(ws + OFF_POSACC);
  float*  negsum  = (float*)(ws + OFF_NEGSUM);
  int*    hist_p  = (int*)  (ws + OFF_HISTP);
  int*    cur_p   = (int*)  (ws + OFF_CURP);
  int*    hist_e  = (int*)  (ws + OFF_HISTE);
  int*    cur_e   = (int*)  (ws + OFF_CURE);
  double* lossd   = (double*)(ws + OFF_LOSS);
  int*    start_p = (int*)  (ws + OFF_STARTP);
  int*    start_e = (int*)  (ws + OFF_STARTE);
  int*    sortpt  = (int*)  (ws + OFF_SORTPT);
  int*    scol    = (int*)  (ws + OFF_SCOL);
  float*  sval    = (float*)(ws + OFF_SVAL);
  float*  cnt     = (float*)(ws + OFF_CNT);
  float*  Xc      = (float*)(ws + OFF_XC);
  float*  hc      = (float*)(ws + OFF_HC);
  float*  t0      = (float*)(ws + OFF_T0);
  float*  qb      = (float*)(ws + OFF_Q);
  float*  hn      = (float*)(ws + OFF_HN);
  float*  negbuf  = (float*)(ws + OFF_NEG);
  u16*    Wt0t    = (u16*)  (ws + OFF_WT0T);
  u16*    Wt1t    = (u16*)  (ws + OFF_WT1T);

  hipMemsetAsync(ws, 0, ZERO_BYTES, stream);

  k_hist<<<(N_PTS+255)/256, 256, 0, stream>>>(pas, N_PTS, hist_p);
  k_hist<<<(E_EDG+255)/256, 256, 0, stream>>>(cgr, E_EDG, hist_e);
  k_scan<<<1, 256, 0, stream>>>(hist_p, start_p);
  k_scan<<<1, 256, 0, stream>>>(hist_e, start_e);
  k_scatter_pts<<<(N_PTS+255)/256, 256, 0, stream>>>(pas, start_p, cur_p, sortpt);
  k_scatter_edges<<<(E_EDG+255)/256, 256, 0, stream>>>(cgr, cgc, cgv, start_e, cur_e, scol, sval);

  k_transpose_bf16<IN_DIM><<<IN_DIM, 256, 0, stream>>>(Wt0, Wt0t);
  k_transpose_bf16<HID  ><<<HID,    256, 0, stream>>>(Wt1, Wt1t);

  k_cluster_agg<<<M_CL, 256, 0, stream>>>(x, pv, sortpt, start_p, Xc, cnt);

  k_gemm_small<512,8,false,true ><<<M_CL/8, 256, 0, stream>>>(Xc, We0, be0, cnt, t0);     // hc_pre
  k_gemm_small<256,8,false,true ><<<M_CL/8, 256, 0, stream>>>(t0, We1, be1, cnt, hc);     // hc
  k_gemm_small<256,8,true ,false><<<M_CL/8, 256, 0, stream>>>(hc, Wp0, bp0, nullptr, t0); // relu
  k_gemm_small<256,8,false,false><<<M_CL/8, 256, 0, stream>>>(t0, Wp1, bp1, nullptr, qb); // q_pre

  k_norm_rows<<<M_CL, 256, 0, stream>>>(qb, qb);  // q
  k_norm_rows<<<M_CL, 256, 0, stream>>>(hc, hn);  // hn

  k_target_mfma<<<(N_PTS+63)/64, 256, 0, stream>>>(x, Wt0t, bt0, Wt1t, bt1, qb, pas, pv, posacc);

  dim3 g2(M_CL/64, M_CL/64);
  k_neg<<<g2, 256, 0, stream>>>(hn, negbuf, negsum);

  k_loss<<<M_CL, 256, 0, stream>>>(negbuf, negsum, posacc, start_e, scol, sval, lossd);
  k_finalize<<<1, 64, 0, stream>>>(lossd, (float*)d_out);
}

// Round 5
// 350.417 us; speedup vs baseline: 2.0402x; 1.0781x over previous
//
#include <hip/hip_runtime.h>
#include <hip/hip_bf16.h>
#include <math.h>

#define N_PTS  100000
#define M_CL   2048
#define E_EDG  65536
#define IN_DIM 512
#define HID    256
// TAU = 0.5 -> 1/TAU = 2.0 ; LAMDA = 1.0 (folded)

typedef unsigned short u16;
typedef __attribute__((ext_vector_type(8))) short bf16x8;
typedef __attribute__((ext_vector_type(4))) float f32x4;

__device__ __forceinline__ u16 f2bf(float f){
  __hip_bfloat16 h = __float2bfloat16(f);
  return *reinterpret_cast<u16*>(&h);
}
__device__ __forceinline__ unsigned pk2(float a, float b){
  return (unsigned)f2bf(a) | ((unsigned)f2bf(b) << 16);
}
__device__ __forceinline__ float bf2f(u16 v){
  return __uint_as_float((unsigned)v << 16);
}
// async global->LDS, 16B per lane. dest must be wave-uniform base + lane*16.
__device__ __forceinline__ void glds16(const u16* g, u16* l){
  __builtin_amdgcn_global_load_lds(
      (const __attribute__((address_space(1))) unsigned int*)(g),
      (__attribute__((address_space(3))) unsigned int*)(l), 16, 0, 0);
}

// ---------------- workspace layout (bytes); ws_size ~819 MB ----------------
static const size_t OFF_POSACC = 0;              // M floats
static const size_t OFF_NEGSUM = 8192;           // M floats
static const size_t OFF_HISTP  = 16384;          // M ints
static const size_t OFF_CURP   = 24576;          // M ints
static const size_t OFF_HISTE  = 32768;          // M ints
static const size_t OFF_CURE   = 40960;          // M ints
static const size_t OFF_LOSS   = 49152;          // 1 double
static const size_t ZERO_BYTES = 49408;
static const size_t OFF_STARTP = 49664;          // M+1 ints
static const size_t OFF_STARTE = 58112;          // M+1 ints
static const size_t OFF_SORTPT = 66560;          // N ints
static const size_t OFF_SCOL   = 466688;         // E ints
static const size_t OFF_SVAL   = 728832;         // E floats
static const size_t OFF_CNT    = 990976;         // M floats
static const size_t OFF_XC     = 999168;         // M*512 f32 = 4 MB (ends 5193472)
static const size_t OFF_Q      = 9387776;        // M*256 f32
static const size_t OFF_HNB    = 11484928;       // M*256 u16 (bf16 hn)
static const size_t OFF_NEGB   = 13582080;       // M*M u16 = 8 MB (ends 21970688)
static const size_t OFF_WT0T   = 22020096;       // 256*512 bf16 = 256 KB
static const size_t OFF_WT1T   = 22282240;       // 256*256 bf16 = 128 KB
static const size_t OFF_XBF    = 33554432;       // N*512 bf16 = 102.4 MB (ends ~136 MB)

// ---------------- CSR build ----------------
__global__ __launch_bounds__(256) void k_hist(const int* __restrict__ idx, int n, int* __restrict__ hist){
  int i = blockIdx.x*256 + threadIdx.x;
  if (i < n) atomicAdd(&hist[idx[i]], 1);
}

__global__ __launch_bounds__(256) void k_scan(const int* __restrict__ hist, int* __restrict__ start){
  __shared__ int part[256];
  int t = threadIdx.x;
  int v[8]; int s = 0;
#pragma unroll
  for (int j=0;j<8;j++){ v[j] = hist[t*8+j]; s += v[j]; }
  part[t] = s;
  __syncthreads();
  if (t == 0){
    int run = 0;
    for (int i=0;i<256;i++){ int tmp = part[i]; part[i] = run; run += tmp; }
  }
  __syncthreads();
  int run = part[t];
#pragma unroll
  for (int j=0;j<8;j++){ start[t*8+j] = run; run += v[j]; }
  if (t == 255) start[M_CL] = run;
}

__global__ __launch_bounds__(256) void k_scatter_pts(const int* __restrict__ assign, const int* __restrict__ start,
                                                     int* __restrict__ cur, int* __restrict__ out){
  int i = blockIdx.x*256 + threadIdx.x;
  if (i < N_PTS){
    int r = assign[i];
    int p = start[r] + atomicAdd(&cur[r], 1);
    out[p] = i;
  }
}

__global__ __launch_bounds__(256) void k_scatter_edges(const int* __restrict__ rows, const int* __restrict__ cols,
                                                       const float* __restrict__ vals, const int* __restrict__ start,
                                                       int* __restrict__ cur, int* __restrict__ scol,
                                                       float* __restrict__ sval){
  int e = blockIdx.x*256 + threadIdx.x;
  if (e < E_EDG){
    int r = rows[e];
    int p = start[r] + atomicAdd(&cur[r], 1);
    scol[p] = cols[e];
    sval[p] = vals[e];
  }
}

// ---------------- Xc = segsum(p*x), cnt = segsum(p), xbf = bf16(x) ----------------
__global__ __launch_bounds__(256) void k_cluster_agg(const float* __restrict__ x, const float* __restrict__ pv,
                                                     const int* __restrict__ sorted_pt, const int* __restrict__ start,
                                                     float* __restrict__ Xc, float* __restrict__ cnt,
                                                     u16* __restrict__ xbf){
  int m = blockIdx.x, t = threadIdx.x;
  int s0 = start[m], s1 = start[m+1];
  float a0 = 0.f, a1 = 0.f, c = 0.f;
  for (int p=s0;p<s1;p++){
    int row = sorted_pt[p];
    float w = pv[row];
    float2 xv = *reinterpret_cast<const float2*>(x + (size_t)row*IN_DIM + t*2);
    a0 = fmaf(w, xv.x, a0);
    a1 = fmaf(w, xv.y, a1);
    c += w;
    *reinterpret_cast<unsigned*>(xbf + (size_t)row*IN_DIM + t*2) = pk2(xv.x, xv.y);
  }
  *reinterpret_cast<float2*>(Xc + (size_t)m*IN_DIM + t*2) = make_float2(a0, a1);
  if (t == 0) cnt[m] = c;
}

// ---------------- weight transpose+convert: W[k][n] f32 -> Wt[n][k] bf16 ----------------
template<int K>
__global__ __launch_bounds__(256) void k_transpose_bf16(const float* __restrict__ W, u16* __restrict__ Wt){
  int o = blockIdx.x*256 + threadIdx.x;   // o = n*K + k
  int n = o / K, k = o % K;
  Wt[o] = f2bf(W[(size_t)k*HID + n]);
}

// ---------------- fused M-scale chain: encoder(2)+projector(2)+both norms ----------------
// 4 rows/block, 512 blocks. Layers hand off via LDS; norms via wave+LDS reduce.
template<int K>
__device__ __forceinline__ void mc_layer(const float* __restrict__ W, const float* act, int t, float acc[4]){
#pragma unroll
  for (int r=0;r<4;r++) acc[r] = 0.f;
#pragma unroll 2
  for (int k=0;k<K;k+=4){
    float w0 = W[(size_t)(k+0)*HID + t];
    float w1 = W[(size_t)(k+1)*HID + t];
    float w2 = W[(size_t)(k+2)*HID + t];
    float w3 = W[(size_t)(k+3)*HID + t];
#pragma unroll
    for (int r=0;r<4;r++){
      float4 av = *reinterpret_cast<const float4*>(act + r*K + k);
      acc[r] = fmaf(av.x, w0, acc[r]);
      acc[r] = fmaf(av.y, w1, acc[r]);
      acc[r] = fmaf(av.z, w2, acc[r]);
      acc[r] = fmaf(av.w, w3, acc[r]);
    }
  }
}

__global__ __launch_bounds__(256) void k_mchain(
    const float* __restrict__ Xc, const float* __restrict__ cnt,
    const float* __restrict__ We0, const float* __restrict__ be0,
    const float* __restrict__ We1, const float* __restrict__ be1,
    const float* __restrict__ Wp0, const float* __restrict__ bp0,
    const float* __restrict__ Wp1, const float* __restrict__ bp1,
    u16* __restrict__ hnb, float* __restrict__ q){
  __shared__ __align__(16) float a_sh[4*512];
  __shared__ __align__(16) float b_sh[4*256];
  __shared__ float part[4][4];
  const int t = threadIdx.x;
  const int rb = blockIdx.x*4;
  for (int i=t; i<4*128; i+=256){
    int r = i>>7, k4 = i&127;
    reinterpret_cast<float4*>(a_sh + r*512)[k4] =
      reinterpret_cast<const float4*>(Xc + (size_t)(rb+r)*IN_DIM)[k4];
  }
  float cv[4];
#pragma unroll
  for (int r=0;r<4;r++) cv[r] = cnt[rb+r];
  __syncthreads();

  float acc[4], v[4];
  // L0: t0 = Xc@We0 + cnt*be0
  mc_layer<512>(We0, a_sh, t, acc);
  {
    float b = be0[t];
#pragma unroll
    for (int r=0;r<4;r++) b_sh[r*256+t] = fmaf(cv[r], b, acc[r]);
  }
  __syncthreads();
  // L1: hc = t0@We1 + cnt*be1 -> hnb (normalized bf16) ; hc -> a_sh for L2
  mc_layer<256>(We1, b_sh, t, acc);
  {
    float b = be1[t];
#pragma unroll
    for (int r=0;r<4;r++){
      v[r] = fmaf(cv[r], b, acc[r]);
      float s = v[r]*v[r];
#pragma unroll
      for (int off=32;off;off>>=1) s += __shfl_xor(s, off, 64);
      if ((t&63) == 0) part[t>>6][r] = s;
      a_sh[r*256+t] = v[r];
    }
  }
  __syncthreads();
#pragma unroll
  for (int r=0;r<4;r++){
    float tot = part[0][r]+part[1][r]+part[2][r]+part[3][r];
    float inv = 1.0f / fmaxf(sqrtf(tot), 1e-12f);
    hnb[(size_t)(rb+r)*HID + t] = f2bf(v[r]*inv);
  }
  // L2: u = relu(hc@Wp0 + bp0)
  mc_layer<256>(Wp0, a_sh, t, acc);
  {
    float b = bp0[t];
#pragma unroll
    for (int r=0;r<4;r++) b_sh[r*256+t] = fmaxf(acc[r]+b, 0.f);
  }
  __syncthreads();
  // L3: q = normalize(u@Wp1 + bp1)
  mc_layer<256>(Wp1, b_sh, t, acc);
  {
    float b = bp1[t];
#pragma unroll
    for (int r=0;r<4;r++){
      v[r] = acc[r] + b;
      float s = v[r]*v[r];
#pragma unroll
      for (int off=32;off;off>>=1) s += __shfl_xor(s, off, 64);
      if ((t&63) == 0) part[t>>6][r] = s;
    }
  }
  __syncthreads();
#pragma unroll
  for (int r=0;r<4;r++){
    float tot = part[0][r]+part[1][r]+part[2][r]+part[3][r];
    float inv = 1.0f / fmaxf(sqrtf(tot), 1e-12f);
    q[(size_t)(rb+r)*HID + t] = v[r]*inv;
  }
}

// ---------------- fused target encoder (block GEMM, all-glds staging) ----------------
// Block: 64m x 256n, 4 waves (wave w = n-slab). K-slabs of 32, double-buffered,
// BOTH operands staged via global_load_lds with pre-swizzled source (m173 pattern).
__global__ __launch_bounds__(256,2) void k_target_mfma(
    const u16* __restrict__ xbf, const u16* __restrict__ Wt0t, const float* __restrict__ bt0,
    const u16* __restrict__ Wt1t, const float* __restrict__ bt1,
    const float* __restrict__ q, const int* __restrict__ assign,
    const float* __restrict__ pv, float* __restrict__ posacc){
  __shared__ u16 ws[2*8192];        // 2 x [256 n][32 k] bf16 = 32 KB
  __shared__ u16 act[16384];        // [64 m][256 n] bf16 = 32 KB; first 8 KB doubles as xs dbuf
  __shared__ float red[2][4][4][16];
  u16* xs = act;                    // xs dbuf: 2 x [64 m][32 k] bf16

  const int t  = threadIdx.x;
  const int w  = t >> 6;
  const int l  = t & 63;
  const int c  = l & 15;
  const int lg = l >> 4;
  const int gm0 = blockIdx.x * 64;

  // x staging: wave w stages slab rows [w*16, w*16+16), pre-swizzled source
  const int sxr = w*16 + (l>>2);
  int sxg = gm0 + sxr; if (sxg >= N_PTS) sxg = N_PTS-1;
  const u16* xsrc = xbf + (size_t)sxg*IN_DIM + ((l&3) ^ ((sxr>>1)&3))*8;
  u16* xdst = xs + (w*64 + l)*8;

  f32x4 acc[4][4];
#pragma unroll
  for (int i=0;i<4;i++)
#pragma unroll
    for (int j=0;j<4;j++){ acc[i][j].x=0.f; acc[i][j].y=0.f; acc[i][j].z=0.f; acc[i][j].w=0.f; }

  #define STAGE_W(Wt, K, k0, buf) do { \
    _Pragma("unroll") \
    for (int i_=0;i_<4;i_++){ \
      int row_ = w*64 + i_*16 + (l>>2); \
      int ug_  = (l&3) ^ ((row_>>1)&3); \
      glds16((Wt) + (size_t)row_*(K) + (k0) + ug_*8, \
             ws + (buf)*8192 + (w*64 + i_*16)*32 + l*8); \
    } } while(0)
  #define STAGE_X(k0, buf) glds16(xsrc + (k0), xdst + (buf)*2048)

  const int su = lg ^ ((c>>1)&3);   // swizzled 16B-unit index for frag reads

  // ================= phase 1: t = x @ Wt0  (K=512, 16 slabs) =================
  STAGE_W(Wt0t, IN_DIM, 0, 0);
  STAGE_X(0, 0);
  __syncthreads();
#pragma unroll
  for (int ks=0; ks<16; ks++){
    int buf = ks & 1;
    if (ks < 15){ STAGE_W(Wt0t, IN_DIM, (ks+1)*32, buf^1); STAGE_X((ks+1)*32, buf^1); }
    bf16x8 bfr[4];
#pragma unroll
    for (int mf=0; mf<4; mf++)
      bfr[mf] = *reinterpret_cast<const bf16x8*>(xs + buf*2048 + ((mf*16+c)*4 + su)*8);
#pragma unroll
    for (int nf=0; nf<4; nf++){
      bf16x8 afr = *reinterpret_cast<const bf16x8*>(ws + buf*8192 + ((w*64+nf*16+c)*4 + su)*8);
#pragma unroll
      for (int mf=0; mf<4; mf++)
        acc[mf][nf] = __builtin_amdgcn_mfma_f32_16x16x32_bf16(afr, bfr[mf], acc[mf][nf], 0,0,0);
    }
    __syncthreads();
  }

  // ---- epilogue-1: acc + bt0 -> act (bf16, unit-swizzled) ----
#pragma unroll
  for (int nf=0; nf<4; nf++){
    f32x4 bias = *reinterpret_cast<const f32x4*>(bt0 + w*64 + nf*16 + lg*4);
#pragma unroll
    for (int mf=0; mf<4; mf++){
      int m = mf*16 + c;
      f32x4 v = acc[mf][nf] + bias;
      uint2 p; p.x = pk2(v.x, v.y); p.y = pk2(v.z, v.w);
      int u = (w*8 + nf*2 + (lg>>1)) ^ (c&7);
      *reinterpret_cast<uint2*>(act + (m*32 + u)*8 + (lg&1)*4) = p;
    }
  }
#pragma unroll
  for (int i=0;i<4;i++)
#pragma unroll
    for (int j=0;j<4;j++){ acc[i][j].x=0.f; acc[i][j].y=0.f; acc[i][j].z=0.f; acc[i][j].w=0.f; }
  STAGE_W(Wt1t, HID, 0, 0);
  __syncthreads();

  // ================= phase 2: v = t @ Wt1  (K=256, 8 slabs) =================
#pragma unroll
  for (int ks=0; ks<8; ks++){
    int buf = ks & 1;
    if (ks < 7) STAGE_W(Wt1t, HID, (ks+1)*32, buf^1);
    bf16x8 bfr[4];
#pragma unroll
    for (int mf=0; mf<4; mf++){
      int m = mf*16 + c;
      int u = (ks*4 + lg) ^ (c&7);
      bfr[mf] = *reinterpret_cast<const bf16x8*>(act + (m*32 + u)*8);
    }
#pragma unroll
    for (int nf=0; nf<4; nf++){
      bf16x8 afr = *reinterpret_cast<const bf16x8*>(ws + buf*8192 + ((w*64+nf*16+c)*4 + su)*8);
#pragma unroll
      for (int mf=0; mf<4; mf++)
        acc[mf][nf] = __builtin_amdgcn_mfma_f32_16x16x32_bf16(afr, bfr[mf], acc[mf][nf], 0,0,0);
    }
    __syncthreads();
  }

  // ---- epilogue-2: +bt1, partial ||v|| and v.q, cross-wave combine ----
#pragma unroll
  for (int mf=0; mf<4; mf++){
    int gm = gm0 + mf*16 + c;
    int cl = assign[(gm < N_PTS) ? gm : (N_PTS-1)];
    const float* qrow = q + (size_t)cl*HID + w*64 + lg*4;
    float ss = 0.f, d = 0.f;
#pragma unroll
    for (int nf=0; nf<4; nf++){
      f32x4 b  = *reinterpret_cast<const f32x4*>(bt1 + w*64 + nf*16 + lg*4);
      f32x4 qv = *reinterpret_cast<const f32x4*>(qrow + nf*16);
      f32x4 v  = acc[mf][nf] + b;
      ss = fmaf(v.x,v.x, fmaf(v.y,v.y, fmaf(v.z,v.z, fmaf(v.w,v.w, ss))));
      d  = fmaf(v.x,qv.x, fmaf(v.y,qv.y, fmaf(v.z,qv.z, fmaf(v.w,qv.w, d))));
    }
    ss += __shfl_xor(ss, 16, 64); ss += __shfl_xor(ss, 32, 64);
    d  += __shfl_xor(d , 16, 64); d  += __shfl_xor(d , 32, 64);
    if (lg == 0){ red[0][w][mf][c] = ss; red[1][w][mf][c] = d; }
  }
  __syncthreads();
  if (t < 64){
    int gm = gm0 + t;
    if (gm < N_PTS){
      int mf = t>>4, cc = t&15;
      float ss = red[0][0][mf][cc]+red[0][1][mf][cc]+red[0][2][mf][cc]+red[0][3][mf][cc];
      float d  = red[1][0][mf][cc]+red[1][1][mf][cc]+red[1][2][mf][cc]+red[1][3][mf][cc];
      float inv = 1.0f / fmaxf(sqrtf(ss), 1e-12f);
      atomicAdd(&posacc[assign[gm]], pv[gm] * d * inv * 2.0f);   // * (1/TAU)
    }
  }
  #undef STAGE_W
  #undef STAGE_X
}

// ---------------- neg = exp(hn@hn^T / TAU) as bf16 + f32 rowsum (MFMA) ----------------
// Block: 64 i x 256 j; same staging structure as k_target phase-2.
__global__ __launch_bounds__(256,2) void k_neg_mfma(
    const u16* __restrict__ hnb, u16* __restrict__ negb, float* __restrict__ negsum){
  __shared__ u16 wsb[2*8192];   // A: [256 j][32 k] dbuf
  __shared__ u16 xsb[2*2048];   // B: [64 i][32 k] dbuf
  const int t  = threadIdx.x;
  const int w  = t >> 6;
  const int l  = t & 63;
  const int c  = l & 15;
  const int lg = l >> 4;
  const int j0 = blockIdx.x * 256;
  const int i0 = blockIdx.y * 64;

  const int sxr = w*16 + (l>>2);
  const u16* xsrc = hnb + (size_t)(i0+sxr)*HID + ((l&3) ^ ((sxr>>1)&3))*8;
  u16* xdst = xsb + (w*64 + l)*8;

  f32x4 acc[4][4];
#pragma unroll
  for (int i=0;i<4;i++)
#pragma unroll
    for (int j=0;j<4;j++){ acc[i][j].x=0.f; acc[i][j].y=0.f; acc[i][j].z=0.f; acc[i][j].w=0.f; }

  #define NSTAGE_W(k0, buf) do { \
    _Pragma("unroll") \
    for (int i_=0;i_<4;i_++){ \
      int row_ = w*64 + i_*16 + (l>>2); \
      int ug_  = (l&3) ^ ((row_>>1)&3); \
      glds16(hnb + (size_t)(j0+row_)*HID + (k0) + ug_*8, \
             wsb + (buf)*8192 + (w*64 + i_*16)*32 + l*8); \
    } } while(0)
  #define NSTAGE_X(k0, buf) glds16(xsrc + (k0), xdst + (buf)*2048)

  NSTAGE_W(0, 0);
  NSTAGE_X(0, 0);
  __syncthreads();
  const int su = lg ^ ((c>>1)&3);
#pragma unroll
  for (int ks=0; ks<8; ks++){
    int buf = ks & 1;
    if (ks < 7){ NSTAGE_W((ks+1)*32, buf^1); NSTAGE_X((ks+1)*32, buf^1); }
    bf16x8 bfr[4];
#pragma unroll
    for (int mf=0; mf<4; mf++)
      bfr[mf] = *reinterpret_cast<const bf16x8*>(xsb + buf*2048 + ((mf*16+c)*4 + su)*8);
#pragma unroll
    for (int nf=0; nf<4; nf++){
      bf16x8 afr = *reinterpret_cast<const bf16x8*>(wsb + buf*8192 + ((w*64+nf*16+c)*4 + su)*8);
#pragma unroll
      for (int mf=0; mf<4; mf++)
        acc[mf][nf] = __builtin_amdgcn_mfma_f32_16x16x32_bf16(afr, bfr[mf], acc[mf][nf], 0,0,0);
    }
    __syncthreads();
  }

#pragma unroll
  for (int mf=0; mf<4; mf++){
    int i = i0 + mf*16 + c;
    float rs = 0.f;
#pragma unroll
    for (int nf=0; nf<4; nf++){
      f32x4 a = acc[mf][nf];
      float e0 = __expf(a.x*2.0f), e1 = __expf(a.y*2.0f);
      float e2 = __expf(a.z*2.0f), e3 = __expf(a.w*2.0f);
      rs += e0+e1+e2+e3;
      uint2 p; p.x = pk2(e0, e1); p.y = pk2(e2, e3);
      *reinterpret_cast<uint2*>(negb + (size_t)i*M_CL + j0 + w*64 + nf*16 + lg*4) = p;
    }
    rs += __shfl_xor(rs, 16, 64); rs += __shfl_xor(rs, 32, 64);
    if (lg == 0) atomicAdd(&negsum[i], rs);
  }
  #undef NSTAGE_W
  #undef NSTAGE_X
}

// ---------------- loss: per row i, gather bf16 partition row + both log terms ----------------
__global__ __launch_bounds__(256) void k_loss(const u16* __restrict__ negb, const float* __restrict__ negsum,
                                              const float* __restrict__ posacc, const int* __restrict__ start,
                                              const int* __restrict__ scol, const float* __restrict__ sval,
                                              double* __restrict__ loss){
  const int i = blockIdx.x, t = threadIdx.x;
  float ps[8] = {};
  const int s0 = start[i], s1 = start[i+1];
  for (int e=s0;e<s1;e++){
    int c = scol[e];
    float v = sval[e];
    const u16* row = negb + (size_t)c*M_CL + t;
#pragma unroll
    for (int jj=0;jj<8;jj++) ps[jj] = fmaf(v, bf2f(row[jj*256]), ps[jj]);
  }
  float pos = __expf(posacc[i]);
  float part = 0.f;
#pragma unroll
  for (int jj=0;jj<8;jj++){
    int j = t + jj*256;
    part += __logf(pos + negsum[j]) - __logf(pos + ps[jj]);  // LAMDA = 1
  }
#pragma unroll
  for (int off=32;off;off>>=1) part += __shfl_xor(part, off, 64);
  __shared__ float wsum[4];
  if ((t&63) == 0) wsum[t>>6] = part;
  __syncthreads();
  if (t == 0){
    double s = (double)wsum[0] + (double)wsum[1] + (double)wsum[2] + (double)wsum[3];
    atomicAdd(loss, s);
  }
}

__global__ void k_finalize(const double* __restrict__ loss, float* __restrict__ out){
  if (threadIdx.x == 0 && blockIdx.x == 0)
    out[0] = (float)(loss[0] / ((double)M_CL * (double)M_CL));
}

// ---------------- launch ----------------
extern "C" void kernel_launch(void* const* d_in, const int* in_sizes, int n_in,
                              void* d_out, int out_size, void* d_ws, size_t ws_size,
                              hipStream_t stream){
  const float* x    = (const float*)d_in[0];
  const float* We0  = (const float*)d_in[1];
  const float* be0  = (const float*)d_in[2];
  const float* We1  = (const float*)d_in[3];
  const float* be1  = (const float*)d_in[4];
  const float* Wt0  = (const float*)d_in[5];
  const float* bt0  = (const float*)d_in[6];
  const float* Wt1  = (const float*)d_in[7];
  const float* bt1  = (const float*)d_in[8];
  const float* Wp0  = (const float*)d_in[9];
  const float* bp0  = (const float*)d_in[10];
  const float* Wp1  = (const float*)d_in[11];
  const float* bp1  = (const float*)d_in[12];
  const float* pv   = (const float*)d_in[13];
  const float* cgv  = (const float*)d_in[14];
  const int*   pas  = (const int*)d_in[15];
  const int*   cgr  = (const int*)d_in[16];
  const int*   cgc  = (const int*)d_in[17];

  char* ws = (char*)d_ws;
  float*  posacc  = (float*)(ws + OFF_POSACC);
  float*  negsum  = (float*)(ws + OFF_NEGSUM);
  int*    hist_p  = (int*)  (ws + OFF_HISTP);
  int*    cur_p   = (int*)  (ws + OFF_CURP);
  int*    hist_e  = (int*)  (ws + OFF_HISTE);
  int*    cur_e   = (int*)  (ws + OFF_CURE);
  double* lossd   = (double*)(ws + OFF_LOSS);
  int*    start_p = (int*)  (ws + OFF_STARTP);
  int*    start_e = (int*)  (ws + OFF_STARTE);
  int*    sortpt  = (int*)  (ws + OFF_SORTPT);
  int*    scol    = (int*)  (ws + OFF_SCOL);
  float*  sval    = (float*)(ws + OFF_SVAL);
  float*  cnt     = (float*)(ws + OFF_CNT);
  float*  Xc      = (float*)(ws + OFF_XC);
  float*  qb      = (float*)(ws + OFF_Q);
  u16*    hnb     = (u16*)  (ws + OFF_HNB);
  u16*    negb    = (u16*)  (ws + OFF_NEGB);
  u16*    Wt0t    = (u16*)  (ws + OFF_WT0T);
  u16*    Wt1t    = (u16*)  (ws + OFF_WT1T);
  u16*    xbf     = (u16*)  (ws + OFF_XBF);

  hipMemsetAsync(ws, 0, ZERO_BYTES, stream);

  k_hist<<<(N_PTS+255)/256, 256, 0, stream>>>(pas, N_PTS, hist_p);
  k_hist<<<(E_EDG+255)/256, 256, 0, stream>>>(cgr, E_EDG, hist_e);
  k_scan<<<1, 256, 0, stream>>>(hist_p, start_p);
  k_scan<<<1, 256, 0, stream>>>(hist_e, start_e);
  k_scatter_pts<<<(N_PTS+255)/256, 256, 0, stream>>>(pas, start_p, cur_p, sortpt);
  k_scatter_edges<<<(E_EDG+255)/256, 256, 0, stream>>>(cgr, cgc, cgv, start_e, cur_e, scol, sval);

  k_transpose_bf16<IN_DIM><<<IN_DIM, 256, 0, stream>>>(Wt0, Wt0t);
  k_transpose_bf16<HID  ><<<HID,    256, 0, stream>>>(Wt1, Wt1t);

  k_cluster_agg<<<M_CL, 256, 0, stream>>>(x, pv, sortpt, start_p, Xc, cnt, xbf);

  k_mchain<<<M_CL/4, 256, 0, stream>>>(Xc, cnt, We0, be0, We1, be1, Wp0, bp0, Wp1, bp1, hnb, qb);

  k_target_mfma<<<(N_PTS+63)/64, 256, 0, stream>>>(xbf, Wt0t, bt0, Wt1t, bt1, qb, pas, pv, posacc);

  dim3 gneg(M_CL/256, M_CL/64);
  k_neg_mfma<<<gneg, 256, 0, stream>>>(hnb, negb, negsum);

  k_loss<<<M_CL, 256, 0, stream>>>(negb, negsum, posacc, start_e, scol, sval, lossd);
  k_finalize<<<1, 64, 0, stream>>>(lossd, (float*)d_out);
}